// Round 3
// baseline (149.175 us; speedup 1.0000x reference)
//
#include <hip/hip_runtime.h>

// DiceCoefficientAll: B=8, N_per_batch=128^3, labels in [0,14)
// ws layout: u32 gcnt[8][3][14]  (hist 0 = count1, 1 = count2, 2 = intersection)

#define NL 14
#define NBATCH 8
constexpr float EPSF = 2.220446049250313e-16f;  // np.finfo(float).eps

// Each block: 256 threads x 32 elements = 8192 contiguous elements.
// 2,097,152 per batch / 8192 = 256 blocks per batch -> batch = blockIdx.x >> 8.
// 2048 blocks / 256 CUs = 8 blocks/CU = 32 waves/CU (full occupancy for BW saturation).
__global__ __launch_bounds__(256) void dice_hist_kernel(
    const float* __restrict__ s1, const float* __restrict__ s2,
    unsigned int* __restrict__ gcnt) {
  __shared__ unsigned int sh[3 * NL];
  const int tid = threadIdx.x;
  if (tid < 3 * NL) sh[tid] = 0;
  __syncthreads();

  // Per-thread packed histograms: 8-bit fields, fields 0..7 in lo, 8..15 in hi.
  // Max 32 increments per field (32 elements/thread) < 255: no overflow.
  unsigned long long c1lo = 0, c1hi = 0;
  unsigned long long c2lo = 0, c2hi = 0;
  unsigned long long cilo = 0, cihi = 0;

  const float4* __restrict__ p1 = (const float4*)s1;
  const float4* __restrict__ p2 = (const float4*)s2;
  const size_t base = (size_t)blockIdx.x * 2048 + tid;

#pragma unroll
  for (int k = 0; k < 8; ++k) {
    float4 a = p1[base + (size_t)k * 256];
    float4 b = p2[base + (size_t)k * 256];
    float av[4] = {a.x, a.y, a.z, a.w};
    float bv[4] = {b.x, b.y, b.z, b.w};
#pragma unroll
    for (int j = 0; j < 4; ++j) {
      int i1 = (int)av[j];
      int i2 = (int)bv[j];
      int ia = (i1 == i2) ? i1 : 14;  // overflow bin for mismatches
      {
        unsigned long long inc = 1ULL << ((i1 << 3) & 63);
        bool h = i1 >= 8;
        c1lo += h ? 0ULL : inc;
        c1hi += h ? inc : 0ULL;
      }
      {
        unsigned long long inc = 1ULL << ((i2 << 3) & 63);
        bool h = i2 >= 8;
        c2lo += h ? 0ULL : inc;
        c2hi += h ? inc : 0ULL;
      }
      {
        unsigned long long inc = 1ULL << ((ia << 3) & 63);
        bool h = ia >= 8;
        cilo += h ? 0ULL : inc;
        cihi += h ? inc : 0ULL;
      }
    }
  }

  // Lane-staggered flush to LDS histogram (spreads 64 lanes across 14 bins).
  const int lane = tid & 63;
  int l = lane % NL;
  for (int j = 0; j < NL; ++j) {
    const int shamt = (l << 3) & 63;
    const bool h = l >= 8;
    unsigned int v1 = (unsigned int)(((h ? c1hi : c1lo) >> shamt) & 0xFF);
    unsigned int v2 = (unsigned int)(((h ? c2hi : c2lo) >> shamt) & 0xFF);
    unsigned int vi = (unsigned int)(((h ? cihi : cilo) >> shamt) & 0xFF);
    atomicAdd(&sh[l], v1);
    atomicAdd(&sh[NL + l], v2);
    atomicAdd(&sh[2 * NL + l], vi);
    ++l;
    if (l >= NL) l = 0;
  }
  __syncthreads();

  if (tid < 3 * NL) {
    const int batch = blockIdx.x >> 8;
    atomicAdd(&gcnt[batch * 3 * NL + tid], sh[tid]);
  }
}

__global__ __launch_bounds__(128) void dice_final_kernel(
    const unsigned int* __restrict__ gcnt, float* __restrict__ out) {
  __shared__ float ssum[128];
  __shared__ int scnt[128];
  const int t = threadIdx.x;
  float v = 0.0f;
  int nz = 0;
  if (t < NBATCH * NL) {
    const int b = t / NL, l = t % NL;
    const unsigned int* g = gcnt + b * 3 * NL;
    const float c1 = (float)g[l];
    const float c2 = (float)g[NL + l];
    const float ci = (float)g[2 * NL + l];
    v = 2.0f * ci / (c1 + c2 + EPSF);
    nz = (v > 0.0f) ? 1 : 0;
  }
  ssum[t] = v;
  scnt[t] = nz;
  __syncthreads();
  for (int s = 64; s > 0; s >>= 1) {
    if (t < s) {
      ssum[t] += ssum[t + s];
      scnt[t] += scnt[t + s];
    }
    __syncthreads();
  }
  if (t == 0) out[0] = scnt[0] ? (ssum[0] / (float)scnt[0]) : 0.0f;
}

extern "C" void kernel_launch(void* const* d_in, const int* in_sizes, int n_in,
                              void* d_out, int out_size, void* d_ws, size_t ws_size,
                              hipStream_t stream) {
  const float* s1 = (const float*)d_in[0];
  const float* s2 = (const float*)d_in[1];
  unsigned int* gcnt = (unsigned int*)d_ws;  // 8*3*14 u32 = 1344 B
  hipMemsetAsync(gcnt, 0, NBATCH * 3 * NL * sizeof(unsigned int), stream);
  const int n = in_sizes[0];              // 16,777,216 expected
  const int blocks = n / 8192;            // 8192 elements per block
  dice_hist_kernel<<<blocks, 256, 0, stream>>>(s1, s2, gcnt);
  dice_final_kernel<<<1, 128, 0, stream>>>(gcnt, (float*)d_out);
}